// Round 1
// 316.140 us; speedup vs baseline: 1.0318x; 1.0318x over previous
//
#include <hip/hip_runtime.h>
#include <stdint.h>

#define NN 32
#define CI 256
#define CO 256
#define HH 56
#define WW 56
#define TPH 58
#define TPW 72
#define CNT (NN*HH*WW)

typedef int i32x4 __attribute__((ext_vector_type(4)));

// async global->LDS 16B (wave-uniform LDS base + lane*16)
__device__ __forceinline__ void gld16(const void* g, void* l) {
    __builtin_amdgcn_global_load_lds(
        (const __attribute__((address_space(1))) void*)(uintptr_t)g,
        (__attribute__((address_space(3))) void*)(uint32_t)(uintptr_t)l,
        16, 0, 0);
}

// ================= 1. per-channel stats, 8-way split over n ==============
__global__ void stats_part(const float* __restrict__ x, double* __restrict__ part) {
    const int c = blockIdx.x, sp = blockIdx.y;           // sp: 4 images each
    double s = 0.0, ss = 0.0;
    const size_t base = ((size_t)(sp * 4) * CI + c) * 3136;
    for (int idx = threadIdx.x; idx < 4 * 784; idx += 256) {
        int nl = idx / 784, q = idx % 784;
        const float4 v = *(const float4*)(x + base + (size_t)nl * CI * 3136 + q * 4);
        double a = v.x, b = v.y, cc = v.z, d = v.w;
        s  += (a + b) + (cc + d);
        ss += (a * a + b * b) + (cc * cc + d * d);
    }
    for (int off = 32; off > 0; off >>= 1) {
        s  += __shfl_down(s, off, 64);
        ss += __shfl_down(ss, off, 64);
    }
    __shared__ double red[8];
    int wid = threadIdx.x >> 6, lane = threadIdx.x & 63;
    if (lane == 0) { red[wid] = s; red[4 + wid] = ss; }
    __syncthreads();
    if (threadIdx.x == 0) {
        part[(sp * 256 + c) * 2]     = (red[0] + red[1]) + (red[2] + red[3]);
        part[(sp * 256 + c) * 2 + 1] = (red[4] + red[5]) + (red[6] + red[7]);
    }
}

// ================= 2. weight quant: per-co int8, layout [tap][chunk][co][ci64]
__global__ void wtrans_kernel(const float* __restrict__ w,
                              int8_t* __restrict__ wT,
                              float* __restrict__ qscale) {
    const int co = blockIdx.x;
    const float* wp = w + (size_t)co * 2304;
    float v[9], m = 0.f;
#pragma unroll
    for (int it = 0; it < 9; ++it) {
        v[it] = wp[threadIdx.x + it * 256];
        m = fmaxf(m, fabsf(v[it]));
    }
    for (int off = 32; off > 0; off >>= 1) m = fmaxf(m, __shfl_down(m, off, 64));
    __shared__ float red[4];
    __shared__ float qsh;
    int wid = threadIdx.x >> 6, lane = threadIdx.x & 63;
    if (lane == 0) red[wid] = m;
    __syncthreads();
    if (threadIdx.x == 0) {
        float mx = fmaxf(fmaxf(red[0], red[1]), fmaxf(red[2], red[3]));
        float q = (mx > 0.f) ? mx / 127.f : 1.f;
        qsh = q;
        qscale[co] = q;
    }
    __syncthreads();
    const float q = qsh;
#pragma unroll
    for (int it = 0; it < 9; ++it) {
        int idx = threadIdx.x + it * 256;
        int ci = idx / 9, tap = idx % 9;
        int chunk = ci >> 6, cis = ci & 63;
        int iq = __float2int_rn(v[it] / q);
        iq = iq > 127 ? 127 : (iq < -127 ? -127 : iq);
        wT[((size_t)(tap * 4 + chunk) * 256 + co) * 64 + cis] = (int8_t)iq;
    }
}

// ========== 3. fused stats-final + ternarize + halo: NCHW -> padded NHWC ==
// grid (58, 32): blockIdx.x = padded row (0 and 57 are halo rows)
__global__ void ternarize_kernel(const float* __restrict__ x,
                                 const double* __restrict__ part,
                                 const float* __restrict__ gamma,
                                 const float* __restrict__ beta,
                                 int8_t* __restrict__ tp) {
    const int h = blockIdx.x, n = blockIdx.y;
    i32x4* rowp = (i32x4*)(tp + ((size_t)n * TPH + h) * TPW * CI);
    if (h == 0 || h == TPH - 1) {                      // halo rows: zero
        const i32x4 z = {0, 0, 0, 0};
        for (int p = threadIdx.x; p < TPW * 16; p += 256) rowp[p] = z;
        return;
    }
    // per-block finalize of channel stats (replaces stats_final kernel)
    __shared__ double Ssc[256], Ssh[256];
    {
        const int c = threadIdx.x;
        double S = 0.0, SS = 0.0;
#pragma unroll
        for (int sp = 0; sp < 8; ++sp) {
            S  += part[(sp * 256 + c) * 2];
            SS += part[(sp * 256 + c) * 2 + 1];
        }
        double mean = S / (double)CNT;
        double var  = SS / (double)CNT - mean * mean;
        double invstd = 1.0 / sqrt(var + 1e-4);
        double scale = (double)gamma[c] * invstd;
        Ssc[c] = scale;
        Ssh[c] = (double)beta[c] - mean * scale;
    }
    __shared__ int8_t L[56 * 260];                     // [w][ci], stride 260
    __syncthreads();
    const int hin = h - 1;
    const size_t xb = ((size_t)n * CI) * 3136 + (size_t)hin * 56;
    // vectorized read: 256 ci x 14 float4
    for (int idx = threadIdx.x; idx < CI * 14; idx += 256) {
        int ci = idx / 14, w4 = idx - ci * 14;
        const float4 v = *(const float4*)(x + xb + (size_t)ci * 3136 + w4 * 4);
        const double sc = Ssc[ci], sh = Ssh[ci];
        const int w = w4 * 4;
        L[(w + 0) * 260 + ci] = (fma(sc, (double)v.x, sh) > 0.0) ? (int8_t)1 : (int8_t)-1;
        L[(w + 1) * 260 + ci] = (fma(sc, (double)v.y, sh) > 0.0) ? (int8_t)1 : (int8_t)-1;
        L[(w + 2) * 260 + ci] = (fma(sc, (double)v.z, sh) > 0.0) ? (int8_t)1 : (int8_t)-1;
        L[(w + 3) * 260 + ci] = (fma(sc, (double)v.w, sh) > 0.0) ? (int8_t)1 : (int8_t)-1;
    }
    __syncthreads();
    for (int p = threadIdx.x; p < TPW * 16; p += 256) {
        int wo = p >> 4, c16 = p & 15;
        i32x4 v = {0, 0, 0, 0};
        if (wo >= 1 && wo <= 56) {
            const int* lp = (const int*)&L[(wo - 1) * 260 + c16 * 16];
            v.x = lp[0]; v.y = lp[1]; v.z = lp[2]; v.w = lp[3];
        }
        rowp[p] = v;
    }
}

// ================= 4. implicit-GEMM conv, int8 MFMA, dbuf LDS =============
// grid (2, 14, 32); block 256 = 4 waves; tile 128co x (4 rows x 64w)
// wave tile: 64co x 64w x 2 rows -> 32 MFMAs per 12 fragment loads.
// B LDS: per ci64-chunk [row6][wp72][64B], ci-16B-slots XOR-swizzled by wp.
#define CONV_LDS (6 * TPW * 64)                        // 27648 B per buffer

__device__ __forceinline__ void stage6(const int8_t* __restrict__ g0,
                                       int8_t* lbuf, int chunk, int tid) {
#pragma unroll
    for (int j = 0; j < 7; ++j) {
        int p = tid + j * 256;                         // 0..1727
        if (j < 6 || tid < 192) {                      // 192 = 3 full waves
            int row = p / 288, rem = p - row * 288;
            int wp = rem >> 2, s = rem & 3;
            int g = (s - wp) & 3;
            gld16(g0 + (size_t)row * TPW * CI + wp * 256 + chunk * 64 + g * 16,
                  lbuf + p * 16);
        }
    }
}

__launch_bounds__(256, 2)
__global__ void conv_kernel(const int8_t* __restrict__ wT,
                            const int8_t* __restrict__ tp,
                            const float* __restrict__ bias,
                            const float* __restrict__ qscale,
                            float* __restrict__ out) {
    const int co_t = blockIdx.x;
    const int h0   = blockIdx.y * 4;
    const int n    = blockIdx.z;
    const int tid  = threadIdx.x;
    const int lane = tid & 63, wid = tid >> 6;
    const int l15 = lane & 15, qd = lane >> 4;
    const int m_off = (wid & 1) * 64;
    const int rs = (wid >> 1) * 2;                     // wave's first output row

    __shared__ __align__(16) int8_t Bsh[2 * CONV_LDS]; // 55296 B, double-buffered

    i32x4 acc[4][4][2];
#pragma unroll
    for (int i = 0; i < 4; ++i)
#pragma unroll
        for (int j = 0; j < 4; ++j)
#pragma unroll
            for (int r = 0; r < 2; ++r) acc[i][j][r] = (i32x4){0, 0, 0, 0};

    const int8_t* g0 = tp + ((size_t)n * TPH + h0) * TPW * CI;

    stage6(g0, Bsh, 0, tid);
    for (int c = 0; c < 4; ++c) {
        __syncthreads();                               // stage(c) done; compute(c-1) done
        if (c < 3) stage6(g0, Bsh + ((c + 1) & 1) * CONV_LDS, c + 1, tid);
        const int8_t* lb = Bsh + (c & 1) * CONV_LDS;
#pragma unroll
        for (int kh = 0; kh < 3; ++kh) {
#pragma unroll
            for (int kw = 0; kw < 3; ++kw) {
                const int tap = kh * 3 + kw;
                const i32x4* ap = (const i32x4*)(wT +
                    ((size_t)(tap * 4 + c) * 256 + co_t * 128 + m_off) * 64);
                i32x4 a[4], b[4][2];
#pragma unroll
                for (int i = 0; i < 4; ++i)
                    a[i] = ap[(i * 16 + l15) * 4 + qd];
#pragma unroll
                for (int j = 0; j < 4; ++j) {
                    const int wp = j * 16 + l15 + kw;
                    const int slot = (qd + wp) & 3;
#pragma unroll
                    for (int r = 0; r < 2; ++r)
                        b[j][r] = *(const i32x4*)&lb[((rs + r + kh) * TPW + wp) * 64 + slot * 16];
                }
                __builtin_amdgcn_s_setprio(1);
#pragma unroll
                for (int i = 0; i < 4; ++i)
#pragma unroll
                    for (int j = 0; j < 4; ++j)
#pragma unroll
                        for (int r = 0; r < 2; ++r)
                            acc[i][j][r] = __builtin_amdgcn_mfma_i32_16x16x64_i8(
                                a[i], b[j][r], acc[i][j][r], 0, 0, 0);
                __builtin_amdgcn_s_setprio(0);
            }
        }
    }

    // epilogue: dequant + bias + relu, fp32 NCHW
    const int h_out = h0 + rs;
#pragma unroll
    for (int i = 0; i < 4; ++i) {
        const int co = co_t * 128 + m_off + i * 16 + qd * 4;
        const float4 bv = *(const float4*)&bias[co];
        const float4 qv = *(const float4*)&qscale[co];
        const float bb[4] = {bv.x, bv.y, bv.z, bv.w};
        const float qq[4] = {qv.x, qv.y, qv.z, qv.w};
#pragma unroll
        for (int j = 0; j < 4; ++j) {
            const int w = j * 16 + l15;
            if (w < 56) {
#pragma unroll
                for (int rr = 0; rr < 2; ++rr) {
                    const size_t ob = (((size_t)n * CO + co) * HH + (h_out + rr)) * WW + w;
#pragma unroll
                    for (int r = 0; r < 4; ++r) {
                        float v = (float)acc[i][j][rr][r] * qq[r] + bb[r];
                        out[ob + (size_t)r * (HH * WW)] = v > 0.f ? v : 0.f;
                    }
                }
            }
        }
    }
}

// ================= launch =================
extern "C" void kernel_launch(void* const* d_in, const int* in_sizes, int n_in,
                              void* d_out, int out_size, void* d_ws, size_t ws_size,
                              hipStream_t stream) {
    const float* x      = (const float*)d_in[0];
    const float* gamma  = (const float*)d_in[1];
    const float* beta   = (const float*)d_in[2];
    const float* weight = (const float*)d_in[3];
    const float* bias   = (const float*)d_in[4];
    float* out = (float*)d_out;

    // workspace layout (16B aligned)
    double* part    = (double*)d_ws;                            // 8*256*2*8 = 32768 B
    float*  qscale  = (float*) ((char*)d_ws + 36864);           // 1024 B
    int8_t* wT      = (int8_t*)((char*)d_ws + 65536);           // 589824 B
    int8_t* tp      = (int8_t*)((char*)d_ws + 1048576);         // 34406400 B

    wtrans_kernel<<<256, 256, 0, stream>>>(weight, wT, qscale);
    stats_part<<<dim3(256, 8), 256, 0, stream>>>(x, part);
    ternarize_kernel<<<dim3(TPH, NN), 256, 0, stream>>>(x, part, gamma, beta, tp);
    conv_kernel<<<dim3(2, 14, NN), 256, 0, stream>>>(wT, tp, bias, qscale, out);
}